// Round 3
// baseline (21055.919 us; speedup 1.0000x reference)
//
#include <hip/hip_runtime.h>
#include <stdint.h>

// Problem dims
#define BB 32
#define SS 2048
#define II 128
#define HH 512
#define OO 128

// Block roles: 16 layer-0 blocks (32 units each), 32 layer-1 blocks (16 units),
// 4 Y blocks (32 out cols). 52 blocks total -> flags poll fits one wave.
#define N0 16
#define N1 32
#define NYB 4
#define NBLK (N0 + N1 + NYB)      // 52
#define PHASES (SS + 2)
#define THREADS 256

// Workspace (bytes): flags[52][4] u32, then tagged h pub buffers, 4-deep slots.
// pub word = (bf16 value << 16) | (phase tag & 0xFFFF)
#define FLAGS_OFF 0
#define H0_OFF    4096
#define H1_OFF    (4096 + 262144)          // [4][32][512] u32 = 256KB each
#define WS_BYTES  (4096 + 2 * 262144)
#define SLOT_W    (BB * HH)                 // 16384 words per slot

// LDS: up to 120KB weight frags (role0) + 6KB split-K reduce (role1)
#define REDOFF    (120 * 1024)
#define LDS_BYTES (120 * 1024 + 6144)

typedef __attribute__((ext_vector_type(8))) short short8;   // 8 x bf16
typedef __attribute__((ext_vector_type(4))) float f32x4;
typedef __attribute__((ext_vector_type(4))) unsigned int u32x4;

__device__ __forceinline__ short f2bf(float f) {
  unsigned int u = __float_as_uint(f);
  u += 0x7fffu + ((u >> 16) & 1u);        // RNE
  return (short)(u >> 16);
}
__device__ __forceinline__ float sigm(float v) { return 1.0f / (1.0f + __expf(-v)); }
__device__ __forceinline__ float tanhc(float v) {
  v = fminf(fmaxf(v, -15.0f), 15.0f);
  float e = __expf(2.0f * v);
  return (e - 1.0f) / (e + 1.0f);
}

// Coherence-point (IC) access, bypassing L1/L2: sc0 sc1.
#define LDG4T(dst_, p_) asm volatile("global_load_dwordx4 %0, %1, off sc0 sc1" : "=&v"(dst_) : "v"(p_))
#define STG4(p_, v_)    asm volatile("global_store_dword %0, %1, off sc0 sc1" :: "v"(p_), "v"(v_))
#define VDRAIN() do { \
  asm volatile("s_waitcnt vmcnt(0)" ::: "memory"); \
  __builtin_amdgcn_sched_barrier(0); \
} while (0)

__device__ __forceinline__ short8 mk_af(u32x4 a, u32x4 b) {
  short8 r;
#pragma unroll
  for (int j = 0; j < 4; ++j) { r[j] = (short)(a[j] >> 16); r[4 + j] = (short)(b[j] >> 16); }
  return r;
}
__device__ __forceinline__ short8 mk_af_x(float4 a, float4 b) {
  short8 r;
  r[0] = f2bf(a.x); r[1] = f2bf(a.y); r[2] = f2bf(a.z); r[3] = f2bf(a.w);
  r[4] = f2bf(b.x); r[5] = f2bf(b.y); r[6] = f2bf(b.z); r[7] = f2bf(b.w);
  return r;
}

// Poll 16 k-tiles (8 words/lane each) until every word's low-16 tag == tag.
// AND-fold is exact: AND of tags == tag iff all tags == tag (stale < tag can't
// cover tag's bits). Data lands in pw[32] (2 x dwordx4 per tile).
__device__ __forceinline__ void poll16(const unsigned int* p0, unsigned int tag, u32x4* pw) {
  for (;;) {
#pragma unroll
    for (int i = 0; i < 16; ++i) {
      LDG4T(pw[2 * i],     p0 + i * 32);
      LDG4T(pw[2 * i + 1], p0 + i * 32 + 4);
    }
    VDRAIN();
    unsigned int a = 0xFFFFFFFFu;
#pragma unroll
    for (int i = 0; i < 32; ++i) a &= pw[i][0] & pw[i][1] & pw[i][2] & pw[i][3];
    if (__all((int)((a & 0xFFFFu) == tag))) return;
  }
}

// Overwrite guard: all 208 wave flags >= thresh (4 flags per lane, lanes>=NBLK pass).
__device__ __forceinline__ void guard_wait(const unsigned int* flags, int l, unsigned int thresh, u32x4 gf) {
  for (;;) {
    unsigned int m0 = gf[0] < gf[1] ? gf[0] : gf[1];
    unsigned int m1 = gf[2] < gf[3] ? gf[2] : gf[3];
    unsigned int mn = m0 < m1 ? m0 : m1;
    bool ok = (l >= NBLK) || (mn >= thresh);
    if (__all((int)ok)) return;
    LDG4T(gf, flags + l * 4);
    VDRAIN();
  }
}

__global__ __launch_bounds__(THREADS, 1)
void gru_persist(const float* __restrict__ x,
                 const float* __restrict__ wx0, const float* __restrict__ bx0,
                 const float* __restrict__ wh0,
                 const float* __restrict__ wx1, const float* __restrict__ bx1,
                 const float* __restrict__ wh1,
                 const float* __restrict__ wy,  const float* __restrict__ by,
                 float* __restrict__ out, unsigned char* __restrict__ ws)
{
  extern __shared__ char smem[];
  short8* ldsw = (short8*)smem;                 // weight frags: frag f at ldsw[(f<<6)+lane]
  float*  red  = (float*)(smem + REDOFF);       // role1 split-K reduce

  unsigned int* flags = (unsigned int*)(ws + FLAGS_OFF);
  unsigned int* pub0  = (unsigned int*)(ws + H0_OFF);
  unsigned int* pub1  = (unsigned int*)(ws + H1_OFF);

  const int tid = threadIdx.x;
  const int l   = tid & 63;
  const int wv  = tid >> 6;
  const int lr  = l & 15;
  const int lg  = l >> 4;
  const int bid = blockIdx.x;
  const int role = (bid < N0) ? 0 : (bid < N0 + N1) ? 1 : 2;
  const int mh = wv & 1;
  const int bA = mh * 16 + lr;        // A-frag batch row
  const int bC = mh * 16 + lg * 4;    // C-frag batch row base
  unsigned int* myflag = flags + bid * 4 + wv;

  // ---------- one-time weight preload into LDS, MFMA B-fragment order ----------
  if (role == 0) {
    for (int f = wv; f < 120; f += 4) {         // [uh(2)][gate(3)][kt(20)]
      const int uh = f / 60, g = (f % 60) / 20, kt = f % 20;
      const int row = g * 512 + bid * 32 + uh * 16 + lr;
      const float* src = (kt < 4) ? (wx0 + (size_t)row * II + kt * 32 + lg * 8)
                                  : (wh0 + (size_t)row * HH + (kt - 4) * 32 + lg * 8);
      short8 v;
#pragma unroll
      for (int j = 0; j < 8; ++j) v[j] = f2bf(src[j]);
      ldsw[(f << 6) + l] = v;
    }
  } else if (role == 1) {
    const int ub = (bid - N0) * 16;
    for (int f = wv; f < 96; f += 4) {          // [gate(3)][kt(32)]
      const int g = f >> 5, kt = f & 31;
      const int row = g * 512 + ub + lr;
      const float* src = (kt < 16) ? (wx1 + (size_t)row * HH + kt * 32 + lg * 8)
                                   : (wh1 + (size_t)row * HH + (kt - 16) * 32 + lg * 8);
      short8 v;
#pragma unroll
      for (int j = 0; j < 8; ++j) v[j] = f2bf(src[j]);
      ldsw[(f << 6) + l] = v;
    }
  } else {
    const int oy = (bid - N0 - N1) * 32;
    for (int f = wv; f < 32; f += 4) {          // [nt(2)][kt(16)]
      const int nt = f >> 4, kt = f & 15;
      const int row = oy + nt * 16 + lr;
      const float* src = wy + (size_t)row * HH + kt * 32 + lg * 8;
      short8 v;
#pragma unroll
      for (int j = 0; j < 8; ++j) v[j] = f2bf(src[j]);
      ldsw[(f << 6) + l] = v;
    }
  }
  __syncthreads();

  if (role == 0) {
    // wave (mh, uh): 16 batches x 16 units, full K=640, no intra-block comm.
    const int uh  = wv >> 1;
    const int u0w = bid * 32 + uh * 16;
    const int fb  = uh * 60;
    const float bz = bx0[u0w + lr], br = bx0[512 + u0w + lr], bg = bx0[1024 + u0w + lr];
    f32x4 hm = {0.f, 0.f, 0.f, 0.f};
    for (int p = 0; p < PHASES; ++p) {
      if (p >= SS) { STG4(myflag, (unsigned)(p + 1)); continue; }
      // x prefetch (immutable input, cached loads)
      const float* xp = x + (size_t)bA * (SS * II) + (size_t)p * II + lg * 8;
      float4 xa[4], xb[4];
#pragma unroll
      for (int t = 0; t < 4; ++t) {
        xa[t] = *(const float4*)(xp + t * 32);
        xb[t] = *(const float4*)(xp + t * 32 + 4);
      }
      u32x4 gf = {0, 0, 0, 0};
      if (p >= 3) LDG4T(gf, flags + l * 4);      // pre-issue guard load
      u32x4 pw[32];
      poll16(pub0 + ((p - 1) & 3) * SLOT_W + bA * HH + lg * 8, (unsigned)p, pw);
      STG4(myflag, (unsigned)(p + 1));           // reads-done flag (fire & forget)
      f32x4 aZ = {0,0,0,0}, aR = {0,0,0,0}, aG1 = {0,0,0,0}, aG2 = {0,0,0,0};
#pragma unroll
      for (int kt = 0; kt < 4; ++kt) {           // x part
        short8 af = mk_af_x(xa[kt], xb[kt]);
        short8 wz = ldsw[((fb + kt) << 6) + l];
        short8 wr = ldsw[((fb + 20 + kt) << 6) + l];
        short8 wg = ldsw[((fb + 40 + kt) << 6) + l];
        aZ  = __builtin_amdgcn_mfma_f32_16x16x32_bf16(af, wz, aZ, 0, 0, 0);
        aR  = __builtin_amdgcn_mfma_f32_16x16x32_bf16(af, wr, aR, 0, 0, 0);
        aG1 = __builtin_amdgcn_mfma_f32_16x16x32_bf16(af, wg, aG1, 0, 0, 0);
      }
#pragma unroll
      for (int i = 0; i < 16; ++i) {             // h part
        const int kt = 4 + i;
        short8 af = mk_af(pw[2 * i], pw[2 * i + 1]);
        short8 wz = ldsw[((fb + kt) << 6) + l];
        short8 wr = ldsw[((fb + 20 + kt) << 6) + l];
        short8 wg = ldsw[((fb + 40 + kt) << 6) + l];
        aZ  = __builtin_amdgcn_mfma_f32_16x16x32_bf16(af, wz, aZ, 0, 0, 0);
        aR  = __builtin_amdgcn_mfma_f32_16x16x32_bf16(af, wr, aR, 0, 0, 0);
        aG2 = __builtin_amdgcn_mfma_f32_16x16x32_bf16(af, wg, aG2, 0, 0, 0);
      }
      if (p >= 3) guard_wait(flags, l, (unsigned)(p - 2), gf);
      unsigned int* po = pub0 + (p & 3) * SLOT_W + u0w + lr;
      const unsigned int tagO = (unsigned)(p + 1);
#pragma unroll
      for (int r = 0; r < 4; ++r) {
        const float zz = sigm(aZ[r] + bz);
        const float rr = sigm(aR[r] + br);
        const float gg = tanhc(aG1[r] + bg + rr * aG2[r]);
        const float hn = gg + zz * (hm[r] - gg);
        hm[r] = hn;
        const unsigned int w = ((unsigned int)(unsigned short)f2bf(hn) << 16) | tagO;
        STG4(po + (size_t)(bC + r) * HH, w);
        if (p == SS - 1)
          out[(size_t)(BB * SS * OO) + (size_t)(bC + r) * (2 * HH) + u0w + lr] = hn;
      }
    }
  } else if (role == 1) {
    // waves (mh, kh): split-K. kh0: h0 part (Z,R,G-x). kh1: h1 part (Z,R,G-h).
    const int kh = wv >> 1;
    const int u0 = (bid - N0) * 16;
    float bz = 0.f, br = 0.f, bg = 0.f;
    if (kh == 0) { bz = bx1[u0 + lr]; br = bx1[512 + u0 + lr]; bg = bx1[1024 + u0 + lr]; }
    f32x4 hm = {0.f, 0.f, 0.f, 0.f};
    for (int p = 0; p < PHASES; ++p) {
      if (p < 1 || p > SS) { STG4(myflag, (unsigned)(p + 1)); continue; }
      u32x4 gf = {0, 0, 0, 0};
      if (kh == 0 && p >= 3) LDG4T(gf, flags + l * 4);
      u32x4 pw[32];
      f32x4 aZ = {0,0,0,0}, aR = {0,0,0,0}, aG1 = {0,0,0,0}, aG2 = {0,0,0,0};
      if (kh == 0) {
        poll16(pub0 + ((p - 1) & 3) * SLOT_W + bA * HH + lg * 8, (unsigned)p, pw);
        STG4(myflag, (unsigned)(p + 1));
#pragma unroll
        for (int kt = 0; kt < 16; ++kt) {
          short8 af = mk_af(pw[2 * kt], pw[2 * kt + 1]);
          short8 wz = ldsw[((0 * 32 + kt) << 6) + l];
          short8 wr = ldsw[((1 * 32 + kt) << 6) + l];
          short8 wg = ldsw[((2 * 32 + kt) << 6) + l];
          aZ  = __builtin_amdgcn_mfma_f32_16x16x32_bf16(af, wz, aZ, 0, 0, 0);
          aR  = __builtin_amdgcn_mfma_f32_16x16x32_bf16(af, wr, aR, 0, 0, 0);
          aG1 = __builtin_amdgcn_mfma_f32_16x16x32_bf16(af, wg, aG1, 0, 0, 0);
        }
      } else {
        poll16(pub1 + ((p - 2) & 3) * SLOT_W + bA * HH + lg * 8, (unsigned)(p - 1), pw);
        STG4(myflag, (unsigned)(p + 1));
#pragma unroll
        for (int i = 0; i < 16; ++i) {
          const int kt = 16 + i;
          short8 af = mk_af(pw[2 * i], pw[2 * i + 1]);
          short8 wz = ldsw[((0 * 32 + kt) << 6) + l];
          short8 wr = ldsw[((1 * 32 + kt) << 6) + l];
          short8 wg = ldsw[((2 * 32 + kt) << 6) + l];
          aZ  = __builtin_amdgcn_mfma_f32_16x16x32_bf16(af, wz, aZ, 0, 0, 0);
          aR  = __builtin_amdgcn_mfma_f32_16x16x32_bf16(af, wr, aR, 0, 0, 0);
          aG2 = __builtin_amdgcn_mfma_f32_16x16x32_bf16(af, wg, aG2, 0, 0, 0);
        }
#pragma unroll
        for (int r = 0; r < 4; ++r) {
          red[((mh * 3 + 0) * 4 + r) * 64 + l] = aZ[r];
          red[((mh * 3 + 1) * 4 + r) * 64 + l] = aR[r];
          red[((mh * 3 + 2) * 4 + r) * 64 + l] = aG2[r];
        }
      }
      __syncthreads();   // red ready. (No 2nd sync needed: kh1's next-phase poll
                         // is gated by kh0's publish, which follows the red read.)
      if (kh == 0) {
        if (p >= 3) guard_wait(flags, l, (unsigned)(p - 2), gf);
        unsigned int* po = pub1 + ((p - 1) & 3) * SLOT_W + u0 + lr;
        const unsigned int tagO = (unsigned)p;
#pragma unroll
        for (int r = 0; r < 4; ++r) {
          const float z2 = red[((mh * 3 + 0) * 4 + r) * 64 + l];
          const float r2 = red[((mh * 3 + 1) * 4 + r) * 64 + l];
          const float g2 = red[((mh * 3 + 2) * 4 + r) * 64 + l];
          const float zz = sigm(aZ[r] + z2 + bz);
          const float rr = sigm(aR[r] + r2 + br);
          const float gg = tanhc(aG1[r] + bg + rr * g2);
          const float hn = gg + zz * (hm[r] - gg);
          hm[r] = hn;
          const unsigned int w = ((unsigned int)(unsigned short)f2bf(hn) << 16) | tagO;
          STG4(po + (size_t)(bC + r) * HH, w);
          if (p == SS)
            out[(size_t)(BB * SS * OO) + (size_t)(bC + r) * (2 * HH) + HH + u0 + lr] = hn;
        }
      }
    }
  } else {
    // Y: y(p-2) = h1(p-2) @ wy^T + by. Never blocks anyone except via flags.
    const int ynt = wv >> 1;
    const int oy  = (bid - N0 - N1) * 32;
    const float byv = by[oy + ynt * 16 + lr];
    for (int p = 0; p < PHASES; ++p) {
      if (p < 2) { STG4(myflag, (unsigned)(p + 1)); continue; }
      u32x4 pw[32];
      poll16(pub1 + ((p - 2) & 3) * SLOT_W + bA * HH + lg * 8, (unsigned)(p - 1), pw);
      STG4(myflag, (unsigned)(p + 1));
      f32x4 acc = {0, 0, 0, 0};
#pragma unroll
      for (int kt = 0; kt < 16; ++kt) {
        short8 bw = ldsw[((ynt * 16 + kt) << 6) + l];
        acc = __builtin_amdgcn_mfma_f32_16x16x32_bf16(mk_af(pw[2 * kt], pw[2 * kt + 1]), bw, acc, 0, 0, 0);
      }
#pragma unroll
      for (int r = 0; r < 4; ++r)
        out[(size_t)(bC + r) * (SS * OO) + (size_t)(p - 2) * OO + oy + ynt * 16 + lr] = acc[r] + byv;
    }
  }
}

extern "C" void kernel_launch(void* const* d_in, const int* in_sizes, int n_in,
                              void* d_out, int out_size, void* d_ws, size_t ws_size,
                              hipStream_t stream) {
  (void)in_sizes; (void)n_in; (void)out_size; (void)ws_size;
  const float* x   = (const float*)d_in[0];
  const float* wx0 = (const float*)d_in[1];
  const float* bx0 = (const float*)d_in[2];
  const float* wh0 = (const float*)d_in[3];
  const float* wx1 = (const float*)d_in[4];
  const float* bx1 = (const float*)d_in[5];
  const float* wh1 = (const float*)d_in[6];
  const float* wy  = (const float*)d_in[7];
  const float* by  = (const float*)d_in[8];
  float* out = (float*)d_out;

  // zero flags + tagged pub buffers (tag 0 == "initial state h=-0", so phase-0
  // polls succeed on memset data; re-zeroing makes every graph replay identical)
  hipMemsetAsync(d_ws, 0, WS_BYTES, stream);
  gru_persist<<<dim3(NBLK), dim3(THREADS), LDS_BYTES, stream>>>(
      x, wx0, bx0, wh0, wx1, bx1, wh1, wy, by, out, (unsigned char*)d_ws);
}

// Round 4
// 16212.694 us; speedup vs baseline: 1.2987x; 1.2987x over previous
//
#include <hip/hip_runtime.h>
#include <stdint.h>

// Problem dims
#define BB 32
#define SS 2048
#define II 128
#define HH 512
#define OO 128

// Block roles: 16 layer-0 blocks (32 units, 4 waves), 32 layer-1 blocks
// (16 units, 2 waves full-K), 4 Y blocks (32 out cols, 4 waves).
#define N0 16
#define N1 32
#define NYB 4
#define NBLK (N0 + N1 + NYB)      // 52
#define THREADS 256

// Workspace (bytes):
//  flags[144] u32 : f0[64] role0 wave flags (=p+1 after publishing h0(p))
//                   f1[64] @+64 role1 wave flags (=p after publishing h1(p-1))
//                   fy[16] @+128 Y wave flags (=p after reads of h1(p-2) retired)
//  pub0 u16[4][32][512] @4096 (4-slot rotation), pub1 same @4096+131072
#define H0_OFF    4096
#define H1_OFF    (4096 + 131072)
#define WS_BYTES  (4096 + 2 * 131072)
#define SLOT_W    (BB * HH)                 // u16 elements per slot

#define LDS_BYTES (120 * 1024)

typedef __attribute__((ext_vector_type(8))) short short8;   // 8 x bf16
typedef __attribute__((ext_vector_type(4))) float f32x4;
typedef __attribute__((ext_vector_type(4))) unsigned int u32x4;

__device__ __forceinline__ short f2bf(float f) {
  unsigned int u = __float_as_uint(f);
  u += 0x7fffu + ((u >> 16) & 1u);        // RNE
  return (short)(u >> 16);
}
__device__ __forceinline__ float sigm(float v) { return 1.0f / (1.0f + __expf(-v)); }
__device__ __forceinline__ float tanhc(float v) {
  v = fminf(fmaxf(v, -15.0f), 15.0f);
  float e = __expf(2.0f * v);
  return (e - 1.0f) / (e + 1.0f);
}

// Coherence-point (IC) access, bypassing L1/L2: sc0 sc1.
#define LDG4T(dst_, p_) asm volatile("global_load_dwordx4 %0, %1, off sc0 sc1" : "=&v"(dst_) : "v"(p_))
#define LDGU(dst_, p_)  asm volatile("global_load_dword %0, %1, off sc0 sc1" : "=&v"(dst_) : "v"(p_))
#define STG2(p_, v_)    asm volatile("global_store_short %0, %1, off sc0 sc1" :: "v"(p_), "v"(v_))
#define STG4(p_, v_)    asm volatile("global_store_dword %0, %1, off sc0 sc1" :: "v"(p_), "v"(v_))
#define VDRAIN() do { \
  asm volatile("s_waitcnt vmcnt(0)" ::: "memory"); \
  __builtin_amdgcn_sched_barrier(0); \
} while (0)

__device__ __forceinline__ short8 mk_af8(u32x4 w) {   // 8 packed bf16 -> short8
  short8 r;
  r[0] = (short)w[0]; r[1] = (short)(w[0] >> 16);
  r[2] = (short)w[1]; r[3] = (short)(w[1] >> 16);
  r[4] = (short)w[2]; r[5] = (short)(w[2] >> 16);
  r[6] = (short)w[3]; r[7] = (short)(w[3] >> 16);
  return r;
}
__device__ __forceinline__ short8 mk_af_x(float4 a, float4 b) {
  short8 r;
  r[0] = f2bf(a.x); r[1] = f2bf(a.y); r[2] = f2bf(a.z); r[3] = f2bf(a.w);
  r[4] = f2bf(b.x); r[5] = f2bf(b.y); r[6] = f2bf(b.z); r[7] = f2bf(b.w);
  return r;
}

__global__ __launch_bounds__(THREADS, 1)
void gru_persist(const float* __restrict__ x,
                 const float* __restrict__ wx0, const float* __restrict__ bx0,
                 const float* __restrict__ wh0,
                 const float* __restrict__ wx1, const float* __restrict__ bx1,
                 const float* __restrict__ wh1,
                 const float* __restrict__ wy,  const float* __restrict__ by,
                 float* __restrict__ out, unsigned char* __restrict__ ws)
{
  extern __shared__ char smem[];
  short8* ldsw = (short8*)smem;                 // weight frags: frag f at ldsw[(f<<6)+lane]

  unsigned int*   flags = (unsigned int*)ws;
  unsigned short* pub0  = (unsigned short*)(ws + H0_OFF);
  unsigned short* pub1  = (unsigned short*)(ws + H1_OFF);

  const int tid = threadIdx.x;
  const int l   = tid & 63;
  const int wv  = tid >> 6;
  const int lr  = l & 15;
  const int lg  = l >> 4;
  const int bid = blockIdx.x;
  const int role = (bid < N0) ? 0 : (bid < N0 + N1) ? 1 : 2;

  // ---------- one-time weight preload into LDS, MFMA B-fragment order ----------
  if (role == 0) {
    for (int f = wv; f < 120; f += 4) {         // [uh(2)][gate(3)][kt(20)]
      const int uh = f / 60, g = (f % 60) / 20, kt = f % 20;
      const int row = g * 512 + bid * 32 + uh * 16 + lr;
      const float* src = (kt < 4) ? (wx0 + (size_t)row * II + kt * 32 + lg * 8)
                                  : (wh0 + (size_t)row * HH + (kt - 4) * 32 + lg * 8);
      short8 v;
#pragma unroll
      for (int j = 0; j < 8; ++j) v[j] = f2bf(src[j]);
      ldsw[(f << 6) + l] = v;
    }
  } else if (role == 1) {
    const int ub = (bid - N0) * 16;
    for (int f = wv; f < 96; f += 4) {          // [gate(3)][kt(32)]: kt<16 = h0-side (wx1), kt>=16 = h1-side (wh1)
      const int g = f >> 5, kt = f & 31;
      const int row = g * 512 + ub + lr;
      const float* src = (kt < 16) ? (wx1 + (size_t)row * HH + kt * 32 + lg * 8)
                                   : (wh1 + (size_t)row * HH + (kt - 16) * 32 + lg * 8);
      short8 v;
#pragma unroll
      for (int j = 0; j < 8; ++j) v[j] = f2bf(src[j]);
      ldsw[(f << 6) + l] = v;
    }
  } else {
    const int oy = (bid - N0 - N1) * 32;
    for (int f = wv; f < 32; f += 4) {          // [nt(2)][kt(16)]
      const int nt = f >> 4, kt = f & 15;
      const int row = oy + nt * 16 + lr;
      const float* src = wy + (size_t)row * HH + kt * 32 + lg * 8;
      short8 v;
#pragma unroll
      for (int j = 0; j < 8; ++j) v[j] = f2bf(src[j]);
      ldsw[(f << 6) + l] = v;
    }
  }
  __syncthreads();

  if (role == 0) {
    // wave (mh, uh): 16 batch rows x 16 units, full K=640.
    const int mh  = wv & 1;
    const int uh  = wv >> 1;
    const int bA  = mh * 16 + lr;
    const int bC  = mh * 16 + lg * 4;
    const int u0w = bid * 32 + uh * 16;
    const int fb  = uh * 60;
    const float bz = bx0[u0w + lr], br = bx0[512 + u0w + lr], bg = bx0[1024 + u0w + lr];
    unsigned int* myflag = flags + bid * 4 + wv;          // f0 slot
    const unsigned int* f0p = flags + l;
    const unsigned int* f1p = flags + 64 + l;
    f32x4 hm = {0.f, 0.f, 0.f, 0.f};

    for (int p = 0; p < SS; ++p) {
      // ---- x-part (cached loads, immutable): 12 MFMAs before the wait ----
      const float* xp = x + (size_t)bA * (SS * II) + (size_t)p * II + lg * 8;
      f32x4 aZ = {0,0,0,0}, aR = {0,0,0,0}, aG1 = {0,0,0,0}, aG2 = {0,0,0,0};
#pragma unroll
      for (int kt = 0; kt < 4; ++kt) {
        short8 af = mk_af_x(*(const float4*)(xp + kt * 32), *(const float4*)(xp + kt * 32 + 4));
        aZ  = __builtin_amdgcn_mfma_f32_16x16x32_bf16(af, ldsw[((fb + kt) << 6) + l], aZ, 0, 0, 0);
        aR  = __builtin_amdgcn_mfma_f32_16x16x32_bf16(af, ldsw[((fb + 20 + kt) << 6) + l], aR, 0, 0, 0);
        aG1 = __builtin_amdgcn_mfma_f32_16x16x32_bf16(af, ldsw[((fb + 40 + kt) << 6) + l], aG1, 0, 0, 0);
      }
      // ---- wait: input h0(p-1) ready (f0 >= p) + slot guard (f1 >= p-3) ----
      const unsigned thrI = (unsigned)p;
      const unsigned thrG = (p >= 3) ? (unsigned)(p - 3) : 0u;
      for (;;) {
        unsigned a, b;
        LDGU(a, f0p); LDGU(b, f1p);
        VDRAIN();
        if (__all((int)((a >= thrI) & (b >= thrG)))) break;
      }
      __builtin_amdgcn_sched_barrier(0);
      // ---- load h0(p-1), one shot ----
      const unsigned short* pb = pub0 + (size_t)((p - 1) & 3) * SLOT_W + bA * HH + lg * 8;
      u32x4 pw[16];
#pragma unroll
      for (int i = 0; i < 16; ++i) LDG4T(pw[i], pb + i * 32);
      VDRAIN();
#pragma unroll
      for (int i = 0; i < 16; ++i) {
        const int kt = 4 + i;
        short8 af = mk_af8(pw[i]);
        aZ  = __builtin_amdgcn_mfma_f32_16x16x32_bf16(af, ldsw[((fb + kt) << 6) + l], aZ, 0, 0, 0);
        aR  = __builtin_amdgcn_mfma_f32_16x16x32_bf16(af, ldsw[((fb + 20 + kt) << 6) + l], aR, 0, 0, 0);
        aG2 = __builtin_amdgcn_mfma_f32_16x16x32_bf16(af, ldsw[((fb + 40 + kt) << 6) + l], aG2, 0, 0, 0);
      }
      // ---- gates + publish h0(p) ----
      unsigned short* po = pub0 + (size_t)(p & 3) * SLOT_W + u0w + lr;
#pragma unroll
      for (int r = 0; r < 4; ++r) {
        const float zz = sigm(aZ[r] + bz);
        const float rr = sigm(aR[r] + br);
        const float gg = tanhc(aG1[r] + bg + rr * aG2[r]);
        const float hn = gg + zz * (hm[r] - gg);
        hm[r] = hn;
        STG2(po + (size_t)(bC + r) * HH, (unsigned int)(unsigned short)f2bf(hn));
        if (p == SS - 1)
          out[(size_t)(BB * SS * OO) + (size_t)(bC + r) * (2 * HH) + u0w + lr] = hn;
      }
      VDRAIN();                                  // release: data at IC before flag
      if (l == 0) STG4(myflag, (unsigned)(p + 1));
    }
  } else if (role == 1) {
    if (wv >= 2) return;                         // 2 full-K waves per block
    const int mh = wv;
    const int bA = mh * 16 + lr;
    const int bC = mh * 16 + lg * 4;
    const int u0 = (bid - N0) * 16;
    const float bz = bx1[u0 + lr], br = bx1[512 + u0 + lr], bg = bx1[1024 + u0 + lr];
    unsigned int* myflag = flags + 64 + (bid - N0) * 2 + wv; // f1 slot
    const unsigned int* f0p = flags + l;
    const unsigned int* f1p = flags + 64 + l;
    const unsigned int* fyp = flags + 128 + (l & 15);
    f32x4 hm = {0.f, 0.f, 0.f, 0.f};

    for (int p = 1; p <= SS; ++p) {
      // ---- wait: h1(p-2) ready (f1 >= p-1, also covers own slot guard) + Y guard ----
      const unsigned thrH = (unsigned)(p - 1);
      const unsigned thrY = (p >= 3) ? (unsigned)(p - 3) : 0u;
      for (;;) {
        unsigned a, b;
        LDGU(a, f1p); LDGU(b, fyp);
        VDRAIN();
        if (__all((int)((a >= thrH) & (b >= thrY)))) break;
      }
      __builtin_amdgcn_sched_barrier(0);
      // ---- issue h1(p-2) loads; they drain inside the f0 poll ----
      const unsigned short* pb1 = pub1 + (size_t)((p - 2) & 3) * SLOT_W + bA * HH + lg * 8;
      u32x4 pw1[16];
#pragma unroll
      for (int i = 0; i < 16; ++i) LDG4T(pw1[i], pb1 + i * 32);
      // ---- wait: h0(p-1) ready ----
      const unsigned thr0 = (unsigned)p;
      for (;;) {
        unsigned a;
        LDGU(a, f0p);
        VDRAIN();
        if (__all((int)(a >= thr0))) break;
      }
      __builtin_amdgcn_sched_barrier(0);
      // ---- issue h0(p-1) loads, compute h1-side MFMAs meanwhile ----
      const unsigned short* pb0 = pub0 + (size_t)((p - 1) & 3) * SLOT_W + bA * HH + lg * 8;
      u32x4 pw0[16];
#pragma unroll
      for (int i = 0; i < 16; ++i) LDG4T(pw0[i], pb0 + i * 32);
      f32x4 aZ = {0,0,0,0}, aR = {0,0,0,0}, aG1 = {0,0,0,0}, aG2 = {0,0,0,0};
#pragma unroll
      for (int i = 0; i < 16; ++i) {             // h1 side: kt 16..31
        const int kt = 16 + i;
        short8 af = mk_af8(pw1[i]);
        aZ  = __builtin_amdgcn_mfma_f32_16x16x32_bf16(af, ldsw[((0 * 32 + kt) << 6) + l], aZ, 0, 0, 0);
        aR  = __builtin_amdgcn_mfma_f32_16x16x32_bf16(af, ldsw[((1 * 32 + kt) << 6) + l], aR, 0, 0, 0);
        aG2 = __builtin_amdgcn_mfma_f32_16x16x32_bf16(af, ldsw[((2 * 32 + kt) << 6) + l], aG2, 0, 0, 0);
      }
      VDRAIN();                                  // pw0 ready
#pragma unroll
      for (int kt = 0; kt < 16; ++kt) {          // h0 side: kt 0..15
        short8 af = mk_af8(pw0[kt]);
        aZ  = __builtin_amdgcn_mfma_f32_16x16x32_bf16(af, ldsw[((0 * 32 + kt) << 6) + l], aZ, 0, 0, 0);
        aR  = __builtin_amdgcn_mfma_f32_16x16x32_bf16(af, ldsw[((1 * 32 + kt) << 6) + l], aR, 0, 0, 0);
        aG1 = __builtin_amdgcn_mfma_f32_16x16x32_bf16(af, ldsw[((2 * 32 + kt) << 6) + l], aG1, 0, 0, 0);
      }
      // ---- gates + publish h1(p-1) ----
      unsigned short* po = pub1 + (size_t)((p - 1) & 3) * SLOT_W + u0 + lr;
#pragma unroll
      for (int r = 0; r < 4; ++r) {
        const float zz = sigm(aZ[r] + bz);
        const float rr = sigm(aR[r] + br);
        const float gg = tanhc(aG1[r] + bg + rr * aG2[r]);
        const float hn = gg + zz * (hm[r] - gg);
        hm[r] = hn;
        STG2(po + (size_t)(bC + r) * HH, (unsigned int)(unsigned short)f2bf(hn));
        if (p == SS)
          out[(size_t)(BB * SS * OO) + (size_t)(bC + r) * (2 * HH) + HH + u0 + lr] = hn;
      }
      VDRAIN();
      if (l == 0) STG4(myflag, (unsigned)p);
    }
  } else {
    // Y: y(p-2) = h1(p-2) @ wy^T + by
    const int mh  = wv & 1;
    const int ynt = wv >> 1;
    const int bA  = mh * 16 + lr;
    const int bC  = mh * 16 + lg * 4;
    const int yb  = bid - N0 - N1;
    const int oy  = yb * 32;
    const float byv = by[oy + ynt * 16 + lr];
    unsigned int* myflag = flags + 128 + yb * 4 + wv;     // fy slot
    const unsigned int* f1p = flags + 64 + l;

    for (int p = 2; p <= SS + 1; ++p) {
      const unsigned thr = (unsigned)(p - 1);
      for (;;) {
        unsigned a;
        LDGU(a, f1p);
        VDRAIN();
        if (__all((int)(a >= thr))) break;
      }
      __builtin_amdgcn_sched_barrier(0);
      const unsigned short* pbV = pub1 + (size_t)((p - 2) & 3) * SLOT_W + bA * HH + lg * 8;
      u32x4 pw[16];
#pragma unroll
      for (int i = 0; i < 16; ++i) LDG4T(pw[i], pbV + i * 32);
      VDRAIN();
      if (l == 0) STG4(myflag, (unsigned)p);     // reads retired -> slot reusable
      f32x4 acc = {0, 0, 0, 0};
#pragma unroll
      for (int kt = 0; kt < 16; ++kt)
        acc = __builtin_amdgcn_mfma_f32_16x16x32_bf16(mk_af8(pw[kt]), ldsw[((ynt * 16 + kt) << 6) + l], acc, 0, 0, 0);
#pragma unroll
      for (int r = 0; r < 4; ++r)
        out[(size_t)(bC + r) * (SS * OO) + (size_t)(p - 2) * OO + oy + ynt * 16 + lr] = acc[r] + byv;
    }
  }
}

extern "C" void kernel_launch(void* const* d_in, const int* in_sizes, int n_in,
                              void* d_out, int out_size, void* d_ws, size_t ws_size,
                              hipStream_t stream) {
  (void)in_sizes; (void)n_in; (void)out_size; (void)ws_size;
  const float* x   = (const float*)d_in[0];
  const float* wx0 = (const float*)d_in[1];
  const float* bx0 = (const float*)d_in[2];
  const float* wh0 = (const float*)d_in[3];
  const float* wx1 = (const float*)d_in[4];
  const float* bx1 = (const float*)d_in[5];
  const float* wh1 = (const float*)d_in[6];
  const float* wy  = (const float*)d_in[7];
  const float* by  = (const float*)d_in[8];
  float* out = (float*)d_out;

  // zero flags + pub buffers (h(-1)=h(-2)=0, flags=0) -> every replay identical
  hipMemsetAsync(d_ws, 0, WS_BYTES, stream);
  gru_persist<<<dim3(NBLK), dim3(THREADS), LDS_BYTES, stream>>>(
      x, wx0, bx0, wh0, wx1, bx1, wh1, wy, by, out, (unsigned char*)d_ws);
}

// Round 5
// 12987.695 us; speedup vs baseline: 1.6212x; 1.2483x over previous
//
#include <hip/hip_runtime.h>
#include <stdint.h>

// Problem dims
#define BB 32
#define SS 2048
#define II 128
#define HH 512
#define OO 128

// Block roles: 16 layer-0 blocks (32 units, 4 waves full-K),
// 32 layer-1 blocks (16 units, 4 waves split-K), 4 Y blocks (32 out cols).
#define N0 16
#define N1 32
#define NYB 4
#define NBLK (N0 + N1 + NYB)      // 52
#define THREADS 256

// Workspace: flags[64] u32 (block-level: [0..15]=f0, [16..47]=f1, [48..51]=fy),
// then pub0/pub1 as 8-slot rotating bf16 [8][32][512].
// Flag semantics: f0[b]=k  <=> h0(k-1) published by block b.
//                 f1[b]=k  <=> h1(k-1) published (role1 phase k done).
//                 fy[b]=k  <=> Y finished loads of h1(k-2).
#define SLOTS 8
#define SLOT_W (BB * HH)                    // u16 per slot
#define H0_OFF 4096
#define H1_OFF (4096 + SLOTS * SLOT_W * 2)  // +262144
#define WS_BYTES (4096 + 2 * SLOTS * SLOT_W * 2)

// LDS: role0 120KB weights; role1 96KB weights + 12KB parity-dbuf reduce.
#define REDOFF    98304
#define LDS_BYTES (120 * 1024)

typedef __attribute__((ext_vector_type(8))) short short8;   // 8 x bf16
typedef __attribute__((ext_vector_type(4))) float f32x4;
typedef __attribute__((ext_vector_type(4))) unsigned int u32x4;

__device__ __forceinline__ short f2bf(float f) {
  unsigned int u = __float_as_uint(f);
  u += 0x7fffu + ((u >> 16) & 1u);        // RNE
  return (short)(u >> 16);
}
__device__ __forceinline__ float sigm(float v) { return 1.0f / (1.0f + __expf(-v)); }
__device__ __forceinline__ float tanhc(float v) {
  v = fminf(fmaxf(v, -15.0f), 15.0f);
  float e = __expf(2.0f * v);
  return (e - 1.0f) / (e + 1.0f);
}

// Coherence-point (IC) access, bypassing L1/L2: sc0 sc1.
#define LDG4T(dst_, p_) asm volatile("global_load_dwordx4 %0, %1, off sc0 sc1" : "=&v"(dst_) : "v"(p_))
#define LDGU(dst_, p_)  asm volatile("global_load_dword %0, %1, off sc0 sc1" : "=&v"(dst_) : "v"(p_))
#define STG2(p_, v_)    asm volatile("global_store_short %0, %1, off sc0 sc1" :: "v"(p_), "v"(v_))
#define STG4(p_, v_)    asm volatile("global_store_dword %0, %1, off sc0 sc1" :: "v"(p_), "v"(v_))
#define VDRAIN() do { \
  asm volatile("s_waitcnt vmcnt(0)" ::: "memory"); \
  __builtin_amdgcn_sched_barrier(0); \
} while (0)

__device__ __forceinline__ short8 mk_af8(u32x4 w) {   // 8 packed bf16 -> short8
  short8 r;
  r[0] = (short)w[0]; r[1] = (short)(w[0] >> 16);
  r[2] = (short)w[1]; r[3] = (short)(w[1] >> 16);
  r[4] = (short)w[2]; r[5] = (short)(w[2] >> 16);
  r[6] = (short)w[3]; r[7] = (short)(w[3] >> 16);
  return r;
}
__device__ __forceinline__ short8 mk_af_x(float4 a, float4 b) {
  short8 r;
  r[0] = f2bf(a.x); r[1] = f2bf(a.y); r[2] = f2bf(a.z); r[3] = f2bf(a.w);
  r[4] = f2bf(b.x); r[5] = f2bf(b.y); r[6] = f2bf(b.z); r[7] = f2bf(b.w);
  return r;
}

// Single-wave merged poll: lane l<16 checks f0>=t0, 16..47 checks f1>=t1,
// 48..51 checks fy>=ty, others pass. s_sleep backoff keeps the flag lines cold.
__device__ __forceinline__ void poll_flags(const unsigned int* flags, int l,
                                           unsigned t0, unsigned t1, unsigned ty) {
  const unsigned thr = (l < 16) ? t0 : (l < 48) ? t1 : (l < 52) ? ty : 0u;
  const unsigned int* fp = flags + ((l < 52) ? l : 0);
  for (;;) {
    unsigned v;
    LDGU(v, fp);
    VDRAIN();
    if (__all((int)(v >= thr))) return;
    __builtin_amdgcn_s_sleep(4);
  }
}

__global__ __launch_bounds__(THREADS, 1)
void gru_persist(const float* __restrict__ x,
                 const float* __restrict__ wx0, const float* __restrict__ bx0,
                 const float* __restrict__ wh0,
                 const float* __restrict__ wx1, const float* __restrict__ bx1,
                 const float* __restrict__ wh1,
                 const float* __restrict__ wy,  const float* __restrict__ by,
                 float* __restrict__ out, unsigned char* __restrict__ ws)
{
  extern __shared__ char smem[];
  short8* ldsw = (short8*)smem;                 // weight frags: frag f at ldsw[(f<<6)+lane]
  float*  red  = (float*)(smem + REDOFF);       // role1 split-K reduce (parity dbuf)

  unsigned int*   flags = (unsigned int*)ws;
  unsigned short* pub0  = (unsigned short*)(ws + H0_OFF);
  unsigned short* pub1  = (unsigned short*)(ws + H1_OFF);

  const int tid = threadIdx.x;
  const int l   = tid & 63;
  const int wv  = tid >> 6;
  const int lr  = l & 15;
  const int lg  = l >> 4;
  const int bid = blockIdx.x;
  const int role = (bid < N0) ? 0 : (bid < N0 + N1) ? 1 : 2;

  // ---------- one-time weight preload into LDS, MFMA B-fragment order ----------
  if (role == 0) {
    for (int f = wv; f < 120; f += 4) {         // [uh(2)][gate(3)][kt(20)]
      const int uh = f / 60, g = (f % 60) / 20, kt = f % 20;
      const int row = g * 512 + bid * 32 + uh * 16 + lr;
      const float* src = (kt < 4) ? (wx0 + (size_t)row * II + kt * 32 + lg * 8)
                                  : (wh0 + (size_t)row * HH + (kt - 4) * 32 + lg * 8);
      short8 v;
#pragma unroll
      for (int j = 0; j < 8; ++j) v[j] = f2bf(src[j]);
      ldsw[(f << 6) + l] = v;
    }
  } else if (role == 1) {
    const int ub = (bid - N0) * 16;
    for (int f = wv; f < 96; f += 4) {          // [gate(3)][kt(32)]: kt<16 h0-side, else h1-side
      const int g = f >> 5, kt = f & 31;
      const int row = g * 512 + ub + lr;
      const float* src = (kt < 16) ? (wx1 + (size_t)row * HH + kt * 32 + lg * 8)
                                   : (wh1 + (size_t)row * HH + (kt - 16) * 32 + lg * 8);
      short8 v;
#pragma unroll
      for (int j = 0; j < 8; ++j) v[j] = f2bf(src[j]);
      ldsw[(f << 6) + l] = v;
    }
  } else {
    const int oy = (bid - N0 - N1) * 32;
    for (int f = wv; f < 32; f += 4) {          // [nt(2)][kt(16)]
      const int nt = f >> 4, kt = f & 15;
      const int row = oy + nt * 16 + lr;
      const float* src = wy + (size_t)row * HH + kt * 32 + lg * 8;
      short8 v;
#pragma unroll
      for (int j = 0; j < 8; ++j) v[j] = f2bf(src[j]);
      ldsw[(f << 6) + l] = v;
    }
  }
  __syncthreads();

  if (role == 0) {
    // wave (mh, uh): 16 batch rows x 16 units, full K=640.
    const int mh  = wv & 1;
    const int uh  = wv >> 1;
    const int bA  = mh * 16 + lr;
    const int bC  = mh * 16 + lg * 4;
    const int u0w = bid * 32 + uh * 16;
    const int fb  = uh * 60;
    const float bz = bx0[u0w + lr], br = bx0[512 + u0w + lr], bg = bx0[1024 + u0w + lr];
    f32x4 hm = {0.f, 0.f, 0.f, 0.f};

    for (int p = 0; p < SS; ++p) {
      // ---- x-part (cached loads, immutable): overlaps the wait ----
      const float* xp = x + (size_t)bA * (SS * II) + (size_t)p * II + lg * 8;
      f32x4 aZ = {0,0,0,0}, aR = {0,0,0,0}, aG1 = {0,0,0,0}, aG2 = {0,0,0,0};
#pragma unroll
      for (int kt = 0; kt < 4; ++kt) {
        short8 af = mk_af_x(*(const float4*)(xp + kt * 32), *(const float4*)(xp + kt * 32 + 4));
        aZ  = __builtin_amdgcn_mfma_f32_16x16x32_bf16(af, ldsw[((fb + kt) << 6) + l], aZ, 0, 0, 0);
        aR  = __builtin_amdgcn_mfma_f32_16x16x32_bf16(af, ldsw[((fb + 20 + kt) << 6) + l], aR, 0, 0, 0);
        aG1 = __builtin_amdgcn_mfma_f32_16x16x32_bf16(af, ldsw[((fb + 40 + kt) << 6) + l], aG1, 0, 0, 0);
      }
      // ---- wait: h0(p-1) ready; slot guard f1 >= p-7 ----
      if (wv == 0) poll_flags(flags, l, (unsigned)p, (p >= 7) ? (unsigned)(p - 7) : 0u, 0u);
      __syncthreads();
      // ---- load h0(p-1) once, then h-part MFMAs ----
      const unsigned short* pb = pub0 + (size_t)((p - 1) & 7) * SLOT_W + bA * HH + lg * 8;
      u32x4 pw[16];
#pragma unroll
      for (int i = 0; i < 16; ++i) LDG4T(pw[i], pb + i * 32);
      VDRAIN();
#pragma unroll
      for (int i = 0; i < 16; ++i) {
        const int kt = 4 + i;
        short8 af = mk_af8(pw[i]);
        aZ  = __builtin_amdgcn_mfma_f32_16x16x32_bf16(af, ldsw[((fb + kt) << 6) + l], aZ, 0, 0, 0);
        aR  = __builtin_amdgcn_mfma_f32_16x16x32_bf16(af, ldsw[((fb + 20 + kt) << 6) + l], aR, 0, 0, 0);
        aG2 = __builtin_amdgcn_mfma_f32_16x16x32_bf16(af, ldsw[((fb + 40 + kt) << 6) + l], aG2, 0, 0, 0);
      }
      // ---- gates + publish h0(p) ----
      unsigned short* po = pub0 + (size_t)(p & 7) * SLOT_W + u0w + lr;
#pragma unroll
      for (int r = 0; r < 4; ++r) {
        const float zz = sigm(aZ[r] + bz);
        const float rr = sigm(aR[r] + br);
        const float gg = tanhc(aG1[r] + bg + rr * aG2[r]);
        const float hn = gg + zz * (hm[r] - gg);
        hm[r] = hn;
        STG2(po + (size_t)(bC + r) * HH, (unsigned int)(unsigned short)f2bf(hn));
        if (p == SS - 1)
          out[(size_t)(BB * SS * OO) + (size_t)(bC + r) * (2 * HH) + u0w + lr] = hn;
      }
      VDRAIN();                                  // data at IC before flag
      __syncthreads();                           // all 4 waves drained
      if (tid == 0) STG4(flags + bid, (unsigned)(p + 1));
    }
  } else if (role == 1) {
    // waves (mh, kh): split-K. kh0 = h0-side (kt 0..15, gets gate-x part aG1),
    // kh1 = h1-side (kt 16..31 -> partials to red).
    const int mh = wv & 1;
    const int kh = wv >> 1;
    const int bA = mh * 16 + lr;
    const int bC = mh * 16 + lg * 4;
    const int u0 = (bid - N0) * 16;
    float bz = 0.f, br = 0.f, bg = 0.f;
    if (kh == 0) { bz = bx1[u0 + lr]; br = bx1[512 + u0 + lr]; bg = bx1[1024 + u0 + lr]; }
    f32x4 hm = {0.f, 0.f, 0.f, 0.f};

    for (int p = 1; p <= SS; ++p) {
      // ---- wait: h0(p-1) (f0>=p), h1(p-2) (f1>=p-1), Y guard (fy>=p-7) ----
      if (wv == 0)
        poll_flags(flags, l, (unsigned)p, (unsigned)(p - 1), (p >= 7) ? (unsigned)(p - 7) : 0u);
      __syncthreads();
      f32x4 aZ = {0,0,0,0}, aR = {0,0,0,0}, aG1 = {0,0,0,0}, aG2 = {0,0,0,0};
      const int par = p & 1;
      if (kh == 0) {
        const unsigned short* pb0 = pub0 + (size_t)((p - 1) & 7) * SLOT_W + bA * HH + lg * 8;
        u32x4 pw[16];
#pragma unroll
        for (int i = 0; i < 16; ++i) LDG4T(pw[i], pb0 + i * 32);
        VDRAIN();
#pragma unroll
        for (int kt = 0; kt < 16; ++kt) {
          short8 af = mk_af8(pw[kt]);
          aZ  = __builtin_amdgcn_mfma_f32_16x16x32_bf16(af, ldsw[((0 * 32 + kt) << 6) + l], aZ, 0, 0, 0);
          aR  = __builtin_amdgcn_mfma_f32_16x16x32_bf16(af, ldsw[((1 * 32 + kt) << 6) + l], aR, 0, 0, 0);
          aG1 = __builtin_amdgcn_mfma_f32_16x16x32_bf16(af, ldsw[((2 * 32 + kt) << 6) + l], aG1, 0, 0, 0);
        }
      } else {
        const unsigned short* pb1 = pub1 + (size_t)((p - 2) & 7) * SLOT_W + bA * HH + lg * 8;
        u32x4 pw[16];
#pragma unroll
        for (int i = 0; i < 16; ++i) LDG4T(pw[i], pb1 + i * 32);
        VDRAIN();
#pragma unroll
        for (int i = 0; i < 16; ++i) {
          const int kt = 16 + i;
          short8 af = mk_af8(pw[i]);
          aZ  = __builtin_amdgcn_mfma_f32_16x16x32_bf16(af, ldsw[((0 * 32 + kt) << 6) + l], aZ, 0, 0, 0);
          aR  = __builtin_amdgcn_mfma_f32_16x16x32_bf16(af, ldsw[((1 * 32 + kt) << 6) + l], aR, 0, 0, 0);
          aG2 = __builtin_amdgcn_mfma_f32_16x16x32_bf16(af, ldsw[((2 * 32 + kt) << 6) + l], aG2, 0, 0, 0);
        }
#pragma unroll
        for (int r = 0; r < 4; ++r) {
          red[(((par * 2 + mh) * 3 + 0) * 4 + r) * 64 + l] = aZ[r];
          red[(((par * 2 + mh) * 3 + 1) * 4 + r) * 64 + l] = aR[r];
          red[(((par * 2 + mh) * 3 + 2) * 4 + r) * 64 + l] = aG2[r];
        }
      }
      __syncthreads();   // red ready (parity dbuf protects against 1-phase skew)
      if (kh == 0) {
        unsigned short* po = pub1 + (size_t)((p - 1) & 7) * SLOT_W + u0 + lr;
#pragma unroll
        for (int r = 0; r < 4; ++r) {
          const float z2 = red[(((par * 2 + mh) * 3 + 0) * 4 + r) * 64 + l];
          const float r2 = red[(((par * 2 + mh) * 3 + 1) * 4 + r) * 64 + l];
          const float g2 = red[(((par * 2 + mh) * 3 + 2) * 4 + r) * 64 + l];
          const float zz = sigm(aZ[r] + z2 + bz);
          const float rr = sigm(aR[r] + r2 + br);
          const float gg = tanhc(aG1[r] + bg + rr * g2);
          const float hn = gg + zz * (hm[r] - gg);
          hm[r] = hn;
          STG2(po + (size_t)(bC + r) * HH, (unsigned int)(unsigned short)f2bf(hn));
          if (p == SS)
            out[(size_t)(BB * SS * OO) + (size_t)(bC + r) * (2 * HH) + HH + u0 + lr] = hn;
        }
        VDRAIN();
      }
      __syncthreads();                           // kh0 publishes drained
      if (tid == 0) STG4(flags + 16 + (bid - N0), (unsigned)p);
    }
  } else {
    // Y: y(p-2) = h1(p-2) @ wy^T + by. Flags after loads retire; compute off-path.
    const int mh  = wv & 1;
    const int ynt = wv >> 1;
    const int bA  = mh * 16 + lr;
    const int bC  = mh * 16 + lg * 4;
    const int yb  = bid - N0 - N1;
    const int oy  = yb * 32;
    const float byv = by[oy + ynt * 16 + lr];

    for (int p = 2; p <= SS + 1; ++p) {
      if (wv == 0) poll_flags(flags, l, 0u, (unsigned)(p - 1), 0u);
      __syncthreads();
      const unsigned short* pbV = pub1 + (size_t)((p - 2) & 7) * SLOT_W + bA * HH + lg * 8;
      u32x4 pw[16];
#pragma unroll
      for (int i = 0; i < 16; ++i) LDG4T(pw[i], pbV + i * 32);
      VDRAIN();
      __syncthreads();                           // all waves' loads retired
      if (tid == 0) STG4(flags + 48 + yb, (unsigned)p);
      f32x4 acc = {0, 0, 0, 0};
#pragma unroll
      for (int kt = 0; kt < 16; ++kt)
        acc = __builtin_amdgcn_mfma_f32_16x16x32_bf16(mk_af8(pw[kt]), ldsw[((ynt * 16 + kt) << 6) + l], acc, 0, 0, 0);
#pragma unroll
      for (int r = 0; r < 4; ++r)
        out[(size_t)(bC + r) * (SS * OO) + (size_t)(p - 2) * OO + oy + ynt * 16 + lr] = acc[r] + byv;
    }
  }
}

extern "C" void kernel_launch(void* const* d_in, const int* in_sizes, int n_in,
                              void* d_out, int out_size, void* d_ws, size_t ws_size,
                              hipStream_t stream) {
  (void)in_sizes; (void)n_in; (void)out_size; (void)ws_size;
  const float* x   = (const float*)d_in[0];
  const float* wx0 = (const float*)d_in[1];
  const float* bx0 = (const float*)d_in[2];
  const float* wh0 = (const float*)d_in[3];
  const float* wx1 = (const float*)d_in[4];
  const float* bx1 = (const float*)d_in[5];
  const float* wh1 = (const float*)d_in[6];
  const float* wy  = (const float*)d_in[7];
  const float* by  = (const float*)d_in[8];
  float* out = (float*)d_out;

  // zero flags + pub buffers (h(-1)=h(-2)=0, flags=0) -> every replay identical
  hipMemsetAsync(d_ws, 0, WS_BYTES, stream);
  gru_persist<<<dim3(NBLK), dim3(THREADS), LDS_BYTES, stream>>>(
      x, wx0, bx0, wh0, wx1, bx1, wh1, wy, by, out, (unsigned char*)d_ws);
}

// Round 6
// 12697.457 us; speedup vs baseline: 1.6583x; 1.0229x over previous
//
#include <hip/hip_runtime.h>
#include <stdint.h>

// Problem dims
#define BB 32
#define SS 2048
#define II 128
#define HH 512
#define OO 128

// Block roles: 16 layer-0 blocks (32 units, 4 waves full-K),
// 32 layer-1 blocks (16 units, 4 waves split-K), 4 Y blocks (32 out cols).
#define N0 16
#define N1 32
#define NYB 4
#define NBLK (N0 + N1 + NYB)      // 52
#define THREADS 256

// Workspace: flags[64] u32 (block-level: [0..15]=f0, [16..47]=f1, [48..51]=fy),
// then pub0/pub1 as 8-slot rotating bf16 [8][32][512].
// Flag semantics: f0[b]=k  <=> h0(k-1) published by block b.
//                 f1[b]=k  <=> h1(k-1) published (role1 phase k done).
//                 fy[b]=k  <=> Y finished loads of h1(k-2).
#define SLOTS 8
#define SLOT_W (BB * HH)                    // u16 per slot
#define H0_OFF 4096
#define H1_OFF (4096 + SLOTS * SLOT_W * 2)  // +262144
#define WS_BYTES (4096 + 2 * SLOTS * SLOT_W * 2)

// LDS: role0 120KB weights; role1 96KB weights + 12KB parity-dbuf reduce.
#define REDOFF    98304
#define LDS_BYTES (120 * 1024)

typedef __attribute__((ext_vector_type(8))) short short8;   // 8 x bf16
typedef __attribute__((ext_vector_type(4))) float f32x4;
typedef __attribute__((ext_vector_type(4))) unsigned int u32x4;

__device__ __forceinline__ short f2bf(float f) {
  unsigned int u = __float_as_uint(f);
  u += 0x7fffu + ((u >> 16) & 1u);        // RNE
  return (short)(u >> 16);
}
__device__ __forceinline__ float sigm(float v) { return 1.0f / (1.0f + __expf(-v)); }
__device__ __forceinline__ float tanhc(float v) {
  v = fminf(fmaxf(v, -15.0f), 15.0f);
  float e = __expf(2.0f * v);
  return (e - 1.0f) / (e + 1.0f);
}

// AGENT-scope (device) access: sc1 only. Bypasses L1+L2 (cross-XCD safe: no
// kernel access to pub/flags ever uses a cached path, so no stale L2/L1 copies
// can exist) but is SERVED + ALLOCATED by the Infinity Cache. R5's sc0sc1
// (system scope) wrote through past the MALL to HBM: WRITE_SIZE showed all
// 134MB of pub stores hitting HBM, making every sync RT HBM-latency class.
#define LDG4T(dst_, p_) asm volatile("global_load_dwordx4 %0, %1, off sc1" : "=&v"(dst_) : "v"(p_))
#define LDGU(dst_, p_)  asm volatile("global_load_dword %0, %1, off sc1" : "=&v"(dst_) : "v"(p_))
#define STG2(p_, v_)    asm volatile("global_store_short %0, %1, off sc1" :: "v"(p_), "v"(v_))
#define STG4(p_, v_)    asm volatile("global_store_dword %0, %1, off sc1" :: "v"(p_), "v"(v_))
#define VDRAIN() do { \
  asm volatile("s_waitcnt vmcnt(0)" ::: "memory"); \
  __builtin_amdgcn_sched_barrier(0); \
} while (0)

__device__ __forceinline__ short8 mk_af8(u32x4 w) {   // 8 packed bf16 -> short8
  short8 r;
  r[0] = (short)w[0]; r[1] = (short)(w[0] >> 16);
  r[2] = (short)w[1]; r[3] = (short)(w[1] >> 16);
  r[4] = (short)w[2]; r[5] = (short)(w[2] >> 16);
  r[6] = (short)w[3]; r[7] = (short)(w[3] >> 16);
  return r;
}
__device__ __forceinline__ short8 mk_af_x(float4 a, float4 b) {
  short8 r;
  r[0] = f2bf(a.x); r[1] = f2bf(a.y); r[2] = f2bf(a.z); r[3] = f2bf(a.w);
  r[4] = f2bf(b.x); r[5] = f2bf(b.y); r[6] = f2bf(b.z); r[7] = f2bf(b.w);
  return r;
}

// Single-wave merged poll: lane l<16 checks f0>=t0, 16..47 checks f1>=t1,
// 48..51 checks fy>=ty, others pass. s_sleep backoff keeps the flag lines cold.
__device__ __forceinline__ void poll_flags(const unsigned int* flags, int l,
                                           unsigned t0, unsigned t1, unsigned ty) {
  const unsigned thr = (l < 16) ? t0 : (l < 48) ? t1 : (l < 52) ? ty : 0u;
  const unsigned int* fp = flags + ((l < 52) ? l : 0);
  for (;;) {
    unsigned v;
    LDGU(v, fp);
    VDRAIN();
    if (__all((int)(v >= thr))) return;
    __builtin_amdgcn_s_sleep(4);
  }
}

__global__ __launch_bounds__(THREADS, 1)
void gru_persist(const float* __restrict__ x,
                 const float* __restrict__ wx0, const float* __restrict__ bx0,
                 const float* __restrict__ wh0,
                 const float* __restrict__ wx1, const float* __restrict__ bx1,
                 const float* __restrict__ wh1,
                 const float* __restrict__ wy,  const float* __restrict__ by,
                 float* __restrict__ out, unsigned char* __restrict__ ws)
{
  extern __shared__ char smem[];
  short8* ldsw = (short8*)smem;                 // weight frags: frag f at ldsw[(f<<6)+lane]
  float*  red  = (float*)(smem + REDOFF);       // role1 split-K reduce (parity dbuf)

  unsigned int*   flags = (unsigned int*)ws;
  unsigned short* pub0  = (unsigned short*)(ws + H0_OFF);
  unsigned short* pub1  = (unsigned short*)(ws + H1_OFF);

  const int tid = threadIdx.x;
  const int l   = tid & 63;
  const int wv  = tid >> 6;
  const int lr  = l & 15;
  const int lg  = l >> 4;
  const int bid = blockIdx.x;
  const int role = (bid < N0) ? 0 : (bid < N0 + N1) ? 1 : 2;

  // ---------- one-time weight preload into LDS, MFMA B-fragment order ----------
  if (role == 0) {
    for (int f = wv; f < 120; f += 4) {         // [uh(2)][gate(3)][kt(20)]
      const int uh = f / 60, g = (f % 60) / 20, kt = f % 20;
      const int row = g * 512 + bid * 32 + uh * 16 + lr;
      const float* src = (kt < 4) ? (wx0 + (size_t)row * II + kt * 32 + lg * 8)
                                  : (wh0 + (size_t)row * HH + (kt - 4) * 32 + lg * 8);
      short8 v;
#pragma unroll
      for (int j = 0; j < 8; ++j) v[j] = f2bf(src[j]);
      ldsw[(f << 6) + l] = v;
    }
  } else if (role == 1) {
    const int ub = (bid - N0) * 16;
    for (int f = wv; f < 96; f += 4) {          // [gate(3)][kt(32)]: kt<16 h0-side, else h1-side
      const int g = f >> 5, kt = f & 31;
      const int row = g * 512 + ub + lr;
      const float* src = (kt < 16) ? (wx1 + (size_t)row * HH + kt * 32 + lg * 8)
                                   : (wh1 + (size_t)row * HH + (kt - 16) * 32 + lg * 8);
      short8 v;
#pragma unroll
      for (int j = 0; j < 8; ++j) v[j] = f2bf(src[j]);
      ldsw[(f << 6) + l] = v;
    }
  } else {
    const int oy = (bid - N0 - N1) * 32;
    for (int f = wv; f < 32; f += 4) {          // [nt(2)][kt(16)]
      const int nt = f >> 4, kt = f & 15;
      const int row = oy + nt * 16 + lr;
      const float* src = wy + (size_t)row * HH + kt * 32 + lg * 8;
      short8 v;
#pragma unroll
      for (int j = 0; j < 8; ++j) v[j] = f2bf(src[j]);
      ldsw[(f << 6) + l] = v;
    }
  }
  __syncthreads();

  if (role == 0) {
    // wave (mh, uh): 16 batch rows x 16 units, full K=640.
    const int mh  = wv & 1;
    const int uh  = wv >> 1;
    const int bA  = mh * 16 + lr;
    const int bC  = mh * 16 + lg * 4;
    const int u0w = bid * 32 + uh * 16;
    const int fb  = uh * 60;
    const float bz = bx0[u0w + lr], br = bx0[512 + u0w + lr], bg = bx0[1024 + u0w + lr];
    f32x4 hm = {0.f, 0.f, 0.f, 0.f};

    for (int p = 0; p < SS; ++p) {
      // ---- x-part (cached loads, immutable): overlaps the wait ----
      const float* xp = x + (size_t)bA * (SS * II) + (size_t)p * II + lg * 8;
      f32x4 aZ = {0,0,0,0}, aR = {0,0,0,0}, aG1 = {0,0,0,0}, aG2 = {0,0,0,0};
#pragma unroll
      for (int kt = 0; kt < 4; ++kt) {
        short8 af = mk_af_x(*(const float4*)(xp + kt * 32), *(const float4*)(xp + kt * 32 + 4));
        aZ  = __builtin_amdgcn_mfma_f32_16x16x32_bf16(af, ldsw[((fb + kt) << 6) + l], aZ, 0, 0, 0);
        aR  = __builtin_amdgcn_mfma_f32_16x16x32_bf16(af, ldsw[((fb + 20 + kt) << 6) + l], aR, 0, 0, 0);
        aG1 = __builtin_amdgcn_mfma_f32_16x16x32_bf16(af, ldsw[((fb + 40 + kt) << 6) + l], aG1, 0, 0, 0);
      }
      // ---- wait: h0(p-1) ready; slot guard f1 >= p-7 ----
      if (wv == 0) poll_flags(flags, l, (unsigned)p, (p >= 7) ? (unsigned)(p - 7) : 0u, 0u);
      __syncthreads();
      // ---- load h0(p-1) once, then h-part MFMAs ----
      const unsigned short* pb = pub0 + (size_t)((p - 1) & 7) * SLOT_W + bA * HH + lg * 8;
      u32x4 pw[16];
#pragma unroll
      for (int i = 0; i < 16; ++i) LDG4T(pw[i], pb + i * 32);
      VDRAIN();
#pragma unroll
      for (int i = 0; i < 16; ++i) {
        const int kt = 4 + i;
        short8 af = mk_af8(pw[i]);
        aZ  = __builtin_amdgcn_mfma_f32_16x16x32_bf16(af, ldsw[((fb + kt) << 6) + l], aZ, 0, 0, 0);
        aR  = __builtin_amdgcn_mfma_f32_16x16x32_bf16(af, ldsw[((fb + 20 + kt) << 6) + l], aR, 0, 0, 0);
        aG2 = __builtin_amdgcn_mfma_f32_16x16x32_bf16(af, ldsw[((fb + 40 + kt) << 6) + l], aG2, 0, 0, 0);
      }
      // ---- gates + publish h0(p) ----
      unsigned short* po = pub0 + (size_t)(p & 7) * SLOT_W + u0w + lr;
#pragma unroll
      for (int r = 0; r < 4; ++r) {
        const float zz = sigm(aZ[r] + bz);
        const float rr = sigm(aR[r] + br);
        const float gg = tanhc(aG1[r] + bg + rr * aG2[r]);
        const float hn = gg + zz * (hm[r] - gg);
        hm[r] = hn;
        STG2(po + (size_t)(bC + r) * HH, (unsigned int)(unsigned short)f2bf(hn));
        if (p == SS - 1)
          out[(size_t)(BB * SS * OO) + (size_t)(bC + r) * (2 * HH) + u0w + lr] = hn;
      }
      VDRAIN();                                  // data at IC before flag
      __syncthreads();                           // all 4 waves drained
      if (tid == 0) STG4(flags + bid, (unsigned)(p + 1));
    }
  } else if (role == 1) {
    // waves (mh, kh): split-K. kh0 = h0-side (kt 0..15, gets gate-x part aG1),
    // kh1 = h1-side (kt 16..31 -> partials to red).
    const int mh = wv & 1;
    const int kh = wv >> 1;
    const int bA = mh * 16 + lr;
    const int bC = mh * 16 + lg * 4;
    const int u0 = (bid - N0) * 16;
    float bz = 0.f, br = 0.f, bg = 0.f;
    if (kh == 0) { bz = bx1[u0 + lr]; br = bx1[512 + u0 + lr]; bg = bx1[1024 + u0 + lr]; }
    f32x4 hm = {0.f, 0.f, 0.f, 0.f};

    for (int p = 1; p <= SS; ++p) {
      // ---- wait: h0(p-1) (f0>=p), h1(p-2) (f1>=p-1), Y guard (fy>=p-7) ----
      if (wv == 0)
        poll_flags(flags, l, (unsigned)p, (unsigned)(p - 1), (p >= 7) ? (unsigned)(p - 7) : 0u);
      __syncthreads();
      f32x4 aZ = {0,0,0,0}, aR = {0,0,0,0}, aG1 = {0,0,0,0}, aG2 = {0,0,0,0};
      const int par = p & 1;
      if (kh == 0) {
        const unsigned short* pb0 = pub0 + (size_t)((p - 1) & 7) * SLOT_W + bA * HH + lg * 8;
        u32x4 pw[16];
#pragma unroll
        for (int i = 0; i < 16; ++i) LDG4T(pw[i], pb0 + i * 32);
        VDRAIN();
#pragma unroll
        for (int kt = 0; kt < 16; ++kt) {
          short8 af = mk_af8(pw[kt]);
          aZ  = __builtin_amdgcn_mfma_f32_16x16x32_bf16(af, ldsw[((0 * 32 + kt) << 6) + l], aZ, 0, 0, 0);
          aR  = __builtin_amdgcn_mfma_f32_16x16x32_bf16(af, ldsw[((1 * 32 + kt) << 6) + l], aR, 0, 0, 0);
          aG1 = __builtin_amdgcn_mfma_f32_16x16x32_bf16(af, ldsw[((2 * 32 + kt) << 6) + l], aG1, 0, 0, 0);
        }
      } else {
        const unsigned short* pb1 = pub1 + (size_t)((p - 2) & 7) * SLOT_W + bA * HH + lg * 8;
        u32x4 pw[16];
#pragma unroll
        for (int i = 0; i < 16; ++i) LDG4T(pw[i], pb1 + i * 32);
        VDRAIN();
#pragma unroll
        for (int i = 0; i < 16; ++i) {
          const int kt = 16 + i;
          short8 af = mk_af8(pw[i]);
          aZ  = __builtin_amdgcn_mfma_f32_16x16x32_bf16(af, ldsw[((0 * 32 + kt) << 6) + l], aZ, 0, 0, 0);
          aR  = __builtin_amdgcn_mfma_f32_16x16x32_bf16(af, ldsw[((1 * 32 + kt) << 6) + l], aR, 0, 0, 0);
          aG2 = __builtin_amdgcn_mfma_f32_16x16x32_bf16(af, ldsw[((2 * 32 + kt) << 6) + l], aG2, 0, 0, 0);
        }
#pragma unroll
        for (int r = 0; r < 4; ++r) {
          red[(((par * 2 + mh) * 3 + 0) * 4 + r) * 64 + l] = aZ[r];
          red[(((par * 2 + mh) * 3 + 1) * 4 + r) * 64 + l] = aR[r];
          red[(((par * 2 + mh) * 3 + 2) * 4 + r) * 64 + l] = aG2[r];
        }
      }
      __syncthreads();   // red ready (parity dbuf protects against 1-phase skew)
      if (kh == 0) {
        unsigned short* po = pub1 + (size_t)((p - 1) & 7) * SLOT_W + u0 + lr;
#pragma unroll
        for (int r = 0; r < 4; ++r) {
          const float z2 = red[(((par * 2 + mh) * 3 + 0) * 4 + r) * 64 + l];
          const float r2 = red[(((par * 2 + mh) * 3 + 1) * 4 + r) * 64 + l];
          const float g2 = red[(((par * 2 + mh) * 3 + 2) * 4 + r) * 64 + l];
          const float zz = sigm(aZ[r] + z2 + bz);
          const float rr = sigm(aR[r] + r2 + br);
          const float gg = tanhc(aG1[r] + bg + rr * g2);
          const float hn = gg + zz * (hm[r] - gg);
          hm[r] = hn;
          STG2(po + (size_t)(bC + r) * HH, (unsigned int)(unsigned short)f2bf(hn));
          if (p == SS)
            out[(size_t)(BB * SS * OO) + (size_t)(bC + r) * (2 * HH) + HH + u0 + lr] = hn;
        }
        VDRAIN();
      }
      __syncthreads();                           // kh0 publishes drained
      if (tid == 0) STG4(flags + 16 + (bid - N0), (unsigned)p);
    }
  } else {
    // Y: y(p-2) = h1(p-2) @ wy^T + by. Flags after loads retire; compute off-path.
    const int mh  = wv & 1;
    const int ynt = wv >> 1;
    const int bA  = mh * 16 + lr;
    const int bC  = mh * 16 + lg * 4;
    const int yb  = bid - N0 - N1;
    const int oy  = yb * 32;
    const float byv = by[oy + ynt * 16 + lr];

    for (int p = 2; p <= SS + 1; ++p) {
      if (wv == 0) poll_flags(flags, l, 0u, (unsigned)(p - 1), 0u);
      __syncthreads();
      const unsigned short* pbV = pub1 + (size_t)((p - 2) & 7) * SLOT_W + bA * HH + lg * 8;
      u32x4 pw[16];
#pragma unroll
      for (int i = 0; i < 16; ++i) LDG4T(pw[i], pbV + i * 32);
      VDRAIN();
      __syncthreads();                           // all waves' loads retired
      if (tid == 0) STG4(flags + 48 + yb, (unsigned)p);
      f32x4 acc = {0, 0, 0, 0};
#pragma unroll
      for (int kt = 0; kt < 16; ++kt)
        acc = __builtin_amdgcn_mfma_f32_16x16x32_bf16(mk_af8(pw[kt]), ldsw[((ynt * 16 + kt) << 6) + l], acc, 0, 0, 0);
#pragma unroll
      for (int r = 0; r < 4; ++r)
        out[(size_t)(bC + r) * (SS * OO) + (size_t)(p - 2) * OO + oy + ynt * 16 + lr] = acc[r] + byv;
    }
  }
}

extern "C" void kernel_launch(void* const* d_in, const int* in_sizes, int n_in,
                              void* d_out, int out_size, void* d_ws, size_t ws_size,
                              hipStream_t stream) {
  (void)in_sizes; (void)n_in; (void)out_size; (void)ws_size;
  const float* x   = (const float*)d_in[0];
  const float* wx0 = (const float*)d_in[1];
  const float* bx0 = (const float*)d_in[2];
  const float* wh0 = (const float*)d_in[3];
  const float* wx1 = (const float*)d_in[4];
  const float* bx1 = (const float*)d_in[5];
  const float* wh1 = (const float*)d_in[6];
  const float* wy  = (const float*)d_in[7];
  const float* by  = (const float*)d_in[8];
  float* out = (float*)d_out;

  // zero flags + pub buffers (h(-1)=h(-2)=0, flags=0) -> every replay identical
  hipMemsetAsync(d_ws, 0, WS_BYTES, stream);
  gru_persist<<<dim3(NBLK), dim3(THREADS), LDS_BYTES, stream>>>(
      x, wx0, bx0, wh0, wx1, bx1, wh1, wy, by, out, (unsigned char*)d_ws);
}

// Round 10
// 12295.321 us; speedup vs baseline: 1.7125x; 1.0327x over previous
//
#include <hip/hip_runtime.h>
#include <stdint.h>

// Problem dims
#define BB 32
#define SS 2048
#define II 128
#define HH 512
#define OO 128

// Block roles: 16 layer-0 blocks (32 units, 4 waves full-K),
// 32 layer-1 blocks (16 units, 4 waves split-K), 4 Y blocks (32 out cols).
#define N0 16
#define N1 32
#define NYB 4
#define NBLK (N0 + N1 + NYB)      // 52
#define THREADS 256

// Workspace: flags[64] u32 (block-level: [0..15]=f0, [16..47]=f1, [48..51]=fy),
// then pub0/pub1 as 8-slot rotating bf16 [8][32][512].
// Flag semantics: f0[b]=k  <=> h0(k-1) published by block b.
//                 f1[b]=k  <=> h1(k-1) published (role1 phase k done).
//                 fy[b]=k  <=> Y finished loads of h1(k-2).
#define SLOTS 8
#define SLOT_W (BB * HH)                    // u16 per slot
#define H0_OFF 4096
#define H1_OFF (4096 + SLOTS * SLOT_W * 2)  // +262144
#define WS_BYTES (4096 + 2 * SLOTS * SLOT_W * 2)

// LDS: role0 120KB weights; role1 96KB weights + 12KB parity-dbuf reduce.
#define REDOFF    98304
#define LDS_BYTES (120 * 1024)

typedef __attribute__((ext_vector_type(8))) short short8;   // 8 x bf16
typedef __attribute__((ext_vector_type(4))) float f32x4;
typedef __attribute__((ext_vector_type(4))) unsigned int u32x4;

__device__ __forceinline__ short f2bf(float f) {
  unsigned int u = __float_as_uint(f);
  u += 0x7fffu + ((u >> 16) & 1u);        // RNE
  return (short)(u >> 16);
}
__device__ __forceinline__ float sigm(float v) { return 1.0f / (1.0f + __expf(-v)); }
__device__ __forceinline__ float tanhc(float v) {
  v = fminf(fmaxf(v, -15.0f), 15.0f);
  float e = __expf(2.0f * v);
  return (e - 1.0f) / (e + 1.0f);
}

// Agent-scope L1/L2-bypass loads (sc1): query the coherence point (MALL).
#define LDG4T(dst_, p_) asm volatile("global_load_dwordx4 %0, %1, off sc1" : "=&v"(dst_) : "v"(p_))
#define LDGU(dst_, p_)  asm volatile("global_load_dword %0, %1, off sc1" : "=&v"(dst_) : "v"(p_))
// Publish path: dword atomic-swap (no sc0 -> no return). Executes AT the MALL and
// leaves the line resident there, so consumer sc1 loads become IC-hits instead of
// HBM fetches (R5/R6 evidence: plain sc1 stores wrote through to HBM -> every
// sync hop paid ~1.3us HBM latency; this is the RT-cutting change of R10).
#define ATSW(p_, v_)    asm volatile("global_atomic_swap %0, %1, off sc1" :: "v"(p_), "v"(v_))
#define VDRAIN() do { \
  asm volatile("s_waitcnt vmcnt(0)" ::: "memory"); \
  __builtin_amdgcn_sched_barrier(0); \
} while (0)

__device__ __forceinline__ short8 mk_af8(u32x4 w) {   // 8 packed bf16 -> short8
  short8 r;
  r[0] = (short)w[0]; r[1] = (short)(w[0] >> 16);
  r[2] = (short)w[1]; r[3] = (short)(w[1] >> 16);
  r[4] = (short)w[2]; r[5] = (short)(w[2] >> 16);
  r[6] = (short)w[3]; r[7] = (short)(w[3] >> 16);
  return r;
}
__device__ __forceinline__ short8 mk_af_x(float4 a, float4 b) {
  short8 r;
  r[0] = f2bf(a.x); r[1] = f2bf(a.y); r[2] = f2bf(a.z); r[3] = f2bf(a.w);
  r[4] = f2bf(b.x); r[5] = f2bf(b.y); r[6] = f2bf(b.z); r[7] = f2bf(b.w);
  return r;
}

// Single-wave merged poll: lane l<16 checks f0>=t0, 16..47 checks f1>=t1,
// 48..51 checks fy>=ty, others pass. No sleep: 52 poller waves on ~3 lines is
// ~1 touch/77ns/line (no congestion); removing the s_sleep(4) tightens detect.
__device__ __forceinline__ void poll_flags(const unsigned int* flags, int l,
                                           unsigned t0, unsigned t1, unsigned ty) {
  const unsigned thr = (l < 16) ? t0 : (l < 48) ? t1 : (l < 52) ? ty : 0u;
  const unsigned int* fp = flags + ((l < 52) ? l : 0);
  for (;;) {
    unsigned v;
    LDGU(v, fp);
    VDRAIN();
    if (__all((int)(v >= thr))) return;
  }
}

__global__ __launch_bounds__(THREADS, 1)
void gru_persist(const float* __restrict__ x,
                 const float* __restrict__ wx0, const float* __restrict__ bx0,
                 const float* __restrict__ wh0,
                 const float* __restrict__ wx1, const float* __restrict__ bx1,
                 const float* __restrict__ wh1,
                 const float* __restrict__ wy,  const float* __restrict__ by,
                 float* __restrict__ out, unsigned char* __restrict__ ws)
{
  extern __shared__ char smem[];
  short8* ldsw = (short8*)smem;                 // weight frags: frag f at ldsw[(f<<6)+lane]
  float*  red  = (float*)(smem + REDOFF);       // role1 split-K reduce (parity dbuf)

  unsigned int*   flagsw = (unsigned int*)ws;
  unsigned short* pub0   = (unsigned short*)(ws + H0_OFF);
  unsigned short* pub1   = (unsigned short*)(ws + H1_OFF);

  const int tid = threadIdx.x;
  const int l   = tid & 63;
  const int wv  = tid >> 6;
  const int lr  = l & 15;
  const int lg  = l >> 4;
  const int bid = blockIdx.x;
  const int role = (bid < N0) ? 0 : (bid < N0 + N1) ? 1 : 2;

  // ---------- one-time weight preload into LDS, MFMA B-fragment order ----------
  if (role == 0) {
    for (int f = wv; f < 120; f += 4) {         // [uh(2)][gate(3)][kt(20)]
      const int uh = f / 60, g = (f % 60) / 20, kt = f % 20;
      const int row = g * 512 + bid * 32 + uh * 16 + lr;
      const float* src = (kt < 4) ? (wx0 + (size_t)row * II + kt * 32 + lg * 8)
                                  : (wh0 + (size_t)row * HH + (kt - 4) * 32 + lg * 8);
      short8 v;
#pragma unroll
      for (int j = 0; j < 8; ++j) v[j] = f2bf(src[j]);
      ldsw[(f << 6) + l] = v;
    }
  } else if (role == 1) {
    const int ub = (bid - N0) * 16;
    for (int f = wv; f < 96; f += 4) {          // [gate(3)][kt(32)]: kt<16 h0-side, else h1-side
      const int g = f >> 5, kt = f & 31;
      const int row = g * 512 + ub + lr;
      const float* src = (kt < 16) ? (wx1 + (size_t)row * HH + kt * 32 + lg * 8)
                                   : (wh1 + (size_t)row * HH + (kt - 16) * 32 + lg * 8);
      short8 v;
#pragma unroll
      for (int j = 0; j < 8; ++j) v[j] = f2bf(src[j]);
      ldsw[(f << 6) + l] = v;
    }
  } else {
    const int oy = (bid - N0 - N1) * 32;
    for (int f = wv; f < 32; f += 4) {          // [nt(2)][kt(16)]
      const int nt = f >> 4, kt = f & 15;
      const int row = oy + nt * 16 + lr;
      const float* src = wy + (size_t)row * HH + kt * 32 + lg * 8;
      short8 v;
#pragma unroll
      for (int j = 0; j < 8; ++j) v[j] = f2bf(src[j]);
      ldsw[(f << 6) + l] = v;
    }
  }
  __syncthreads();

  if (role == 0) {
    // wave (mh, uh): 16 batch rows x 16 units, full K=640.
    const int mh  = wv & 1;
    const int uh  = wv >> 1;
    const int bA  = mh * 16 + lr;
    const int bC  = mh * 16 + lg * 4;
    const int u0w = bid * 32 + uh * 16;
    const int fb  = uh * 60;
    const float bz = bx0[u0w + lr], br = bx0[512 + u0w + lr], bg = bx0[1024 + u0w + lr];
    f32x4 hm = {0.f, 0.f, 0.f, 0.f};

    for (int p = 0; p < SS; ++p) {
      // ---- x-part (cached loads, immutable): overlaps the wait ----
      const float* xp = x + (size_t)bA * (SS * II) + (size_t)p * II + lg * 8;
      f32x4 aZ = {0,0,0,0}, aR = {0,0,0,0}, aG1 = {0,0,0,0}, aG2 = {0,0,0,0};
#pragma unroll
      for (int kt = 0; kt < 4; ++kt) {
        short8 af = mk_af_x(*(const float4*)(xp + kt * 32), *(const float4*)(xp + kt * 32 + 4));
        aZ  = __builtin_amdgcn_mfma_f32_16x16x32_bf16(af, ldsw[((fb + kt) << 6) + l], aZ, 0, 0, 0);
        aR  = __builtin_amdgcn_mfma_f32_16x16x32_bf16(af, ldsw[((fb + 20 + kt) << 6) + l], aR, 0, 0, 0);
        aG1 = __builtin_amdgcn_mfma_f32_16x16x32_bf16(af, ldsw[((fb + 40 + kt) << 6) + l], aG1, 0, 0, 0);
      }
      // ---- wait: h0(p-1) ready; slot guard f1 >= p-7 ----
      if (wv == 0) poll_flags(flagsw, l, (unsigned)p, (p >= 7) ? (unsigned)(p - 7) : 0u, 0u);
      __syncthreads();
      // ---- load h0(p-1) once, then h-part MFMAs ----
      const unsigned short* pb = pub0 + (size_t)((p - 1) & 7) * SLOT_W + bA * HH + lg * 8;
      u32x4 pw[16];
#pragma unroll
      for (int i = 0; i < 16; ++i) LDG4T(pw[i], pb + i * 32);
      VDRAIN();
#pragma unroll
      for (int i = 0; i < 16; ++i) {
        const int kt = 4 + i;
        short8 af = mk_af8(pw[i]);
        aZ  = __builtin_amdgcn_mfma_f32_16x16x32_bf16(af, ldsw[((fb + kt) << 6) + l], aZ, 0, 0, 0);
        aR  = __builtin_amdgcn_mfma_f32_16x16x32_bf16(af, ldsw[((fb + 20 + kt) << 6) + l], aR, 0, 0, 0);
        aG2 = __builtin_amdgcn_mfma_f32_16x16x32_bf16(af, ldsw[((fb + 40 + kt) << 6) + l], aG2, 0, 0, 0);
      }
      // ---- gates + publish h0(p) via packed-dword atomic-swap ----
#pragma unroll
      for (int r = 0; r < 4; ++r) {
        const float zz = sigm(aZ[r] + bz);
        const float rr = sigm(aR[r] + br);
        const float gg = tanhc(aG1[r] + bg + rr * aG2[r]);
        const float hn = gg + zz * (hm[r] - gg);
        hm[r] = hn;
        const unsigned mine = (unsigned)(unsigned short)f2bf(hn);
        const unsigned oth  = __shfl_xor(mine, 1);           // partner col (lr^1), same row
        if (!(lr & 1)) {
          unsigned int* dp = (unsigned int*)(pub0 + (size_t)(p & 7) * SLOT_W
                                             + (size_t)(bC + r) * HH + u0w + lr);
          ATSW(dp, mine | (oth << 16));                      // low u16 = even col (LE)
        }
        if (p == SS - 1)
          out[(size_t)(BB * SS * OO) + (size_t)(bC + r) * (2 * HH) + u0w + lr] = hn;
      }
      VDRAIN();                                  // pub atomics done at MALL before flag
      __syncthreads();                           // all 4 waves drained
      if (tid == 0) ATSW(flagsw + bid, (unsigned)(p + 1));
    }
  } else if (role == 1) {
    // waves (mh, kh): split-K. kh0 = h0-side (kt 0..15, gate-x part aG1) + publish,
    // kh1 = h1-side (kt 16..31 -> partials to red, parity dbuf).
    const int mh = wv & 1;
    const int kh = wv >> 1;
    const int bA = mh * 16 + lr;
    const int bC = mh * 16 + lg * 4;
    const int u0 = (bid - N0) * 16;
    float bz = 0.f, br = 0.f, bg = 0.f;
    if (kh == 0) { bz = bx1[u0 + lr]; br = bx1[512 + u0 + lr]; bg = bx1[1024 + u0 + lr]; }
    f32x4 hm = {0.f, 0.f, 0.f, 0.f};

    for (int p = 1; p <= SS; ++p) {
      // ---- wait: h0(p-1) (f0>=p), h1(p-2) (f1>=p-1), Y guard (fy>=p-7) ----
      if (wv == 0)
        poll_flags(flagsw, l, (unsigned)p, (unsigned)(p - 1), (p >= 7) ? (unsigned)(p - 7) : 0u);
      __syncthreads();
      f32x4 aZ = {0,0,0,0}, aR = {0,0,0,0}, aG1 = {0,0,0,0}, aG2 = {0,0,0,0};
      const int par = p & 1;
      if (kh == 0) {
        const unsigned short* pb0 = pub0 + (size_t)((p - 1) & 7) * SLOT_W + bA * HH + lg * 8;
        u32x4 pw[16];
#pragma unroll
        for (int i = 0; i < 16; ++i) LDG4T(pw[i], pb0 + i * 32);
        VDRAIN();
#pragma unroll
        for (int kt = 0; kt < 16; ++kt) {
          short8 af = mk_af8(pw[kt]);
          aZ  = __builtin_amdgcn_mfma_f32_16x16x32_bf16(af, ldsw[((0 * 32 + kt) << 6) + l], aZ, 0, 0, 0);
          aR  = __builtin_amdgcn_mfma_f32_16x16x32_bf16(af, ldsw[((1 * 32 + kt) << 6) + l], aR, 0, 0, 0);
          aG1 = __builtin_amdgcn_mfma_f32_16x16x32_bf16(af, ldsw[((2 * 32 + kt) << 6) + l], aG1, 0, 0, 0);
        }
      } else {
        const unsigned short* pb1 = pub1 + (size_t)((p - 2) & 7) * SLOT_W + bA * HH + lg * 8;
        u32x4 pw[16];
#pragma unroll
        for (int i = 0; i < 16; ++i) LDG4T(pw[i], pb1 + i * 32);
        VDRAIN();
#pragma unroll
        for (int i = 0; i < 16; ++i) {
          const int kt = 16 + i;
          short8 af = mk_af8(pw[i]);
          aZ  = __builtin_amdgcn_mfma_f32_16x16x32_bf16(af, ldsw[((0 * 32 + kt) << 6) + l], aZ, 0, 0, 0);
          aR  = __builtin_amdgcn_mfma_f32_16x16x32_bf16(af, ldsw[((1 * 32 + kt) << 6) + l], aR, 0, 0, 0);
          aG2 = __builtin_amdgcn_mfma_f32_16x16x32_bf16(af, ldsw[((2 * 32 + kt) << 6) + l], aG2, 0, 0, 0);
        }
#pragma unroll
        for (int r = 0; r < 4; ++r) {
          red[(((par * 2 + mh) * 3 + 0) * 4 + r) * 64 + l] = aZ[r];
          red[(((par * 2 + mh) * 3 + 1) * 4 + r) * 64 + l] = aR[r];
          red[(((par * 2 + mh) * 3 + 2) * 4 + r) * 64 + l] = aG2[r];
        }
      }
      __syncthreads();   // red ready (parity dbuf protects against 1-phase skew)
      if (kh == 0) {
#pragma unroll
        for (int r = 0; r < 4; ++r) {
          const float z2 = red[(((par * 2 + mh) * 3 + 0) * 4 + r) * 64 + l];
          const float r2 = red[(((par * 2 + mh) * 3 + 1) * 4 + r) * 64 + l];
          const float g2 = red[(((par * 2 + mh) * 3 + 2) * 4 + r) * 64 + l];
          const float zz = sigm(aZ[r] + z2 + bz);
          const float rr = sigm(aR[r] + r2 + br);
          const float gg = tanhc(aG1[r] + bg + rr * g2);
          const float hn = gg + zz * (hm[r] - gg);
          hm[r] = hn;
          const unsigned mine = (unsigned)(unsigned short)f2bf(hn);
          const unsigned oth  = __shfl_xor(mine, 1);
          if (!(lr & 1)) {
            unsigned int* dp = (unsigned int*)(pub1 + (size_t)((p - 1) & 7) * SLOT_W
                                               + (size_t)(bC + r) * HH + u0 + lr);
            ATSW(dp, mine | (oth << 16));
          }
          if (p == SS)
            out[(size_t)(BB * SS * OO) + (size_t)(bC + r) * (2 * HH) + HH + u0 + lr] = hn;
        }
        VDRAIN();
      }
      __syncthreads();                           // kh0 publishes drained
      if (tid == 0) ATSW(flagsw + 16 + (bid - N0), (unsigned)p);
    }
  } else {
    // Y: y(p-2) = h1(p-2) @ wy^T + by. Flags after loads retire; compute off-path.
    const int mh  = wv & 1;
    const int ynt = wv >> 1;
    const int bA  = mh * 16 + lr;
    const int bC  = mh * 16 + lg * 4;
    const int yb  = bid - N0 - N1;
    const int oy  = yb * 32;
    const float byv = by[oy + ynt * 16 + lr];

    for (int p = 2; p <= SS + 1; ++p) {
      if (wv == 0) poll_flags(flagsw, l, 0u, (unsigned)(p - 1), 0u);
      __syncthreads();
      const unsigned short* pbV = pub1 + (size_t)((p - 2) & 7) * SLOT_W + bA * HH + lg * 8;
      u32x4 pw[16];
#pragma unroll
      for (int i = 0; i < 16; ++i) LDG4T(pw[i], pbV + i * 32);
      VDRAIN();
      __syncthreads();                           // all waves' loads retired
      if (tid == 0) ATSW(flagsw + 48 + yb, (unsigned)p);
      f32x4 acc = {0, 0, 0, 0};
#pragma unroll
      for (int kt = 0; kt < 16; ++kt)
        acc = __builtin_amdgcn_mfma_f32_16x16x32_bf16(mk_af8(pw[kt]), ldsw[((ynt * 16 + kt) << 6) + l], acc, 0, 0, 0);
#pragma unroll
      for (int r = 0; r < 4; ++r)
        out[(size_t)(bC + r) * (SS * OO) + (size_t)(p - 2) * OO + oy + ynt * 16 + lr] = acc[r] + byv;
    }
  }
}

extern "C" void kernel_launch(void* const* d_in, const int* in_sizes, int n_in,
                              void* d_out, int out_size, void* d_ws, size_t ws_size,
                              hipStream_t stream) {
  (void)in_sizes; (void)n_in; (void)out_size; (void)ws_size;
  const float* x   = (const float*)d_in[0];
  const float* wx0 = (const float*)d_in[1];
  const float* bx0 = (const float*)d_in[2];
  const float* wh0 = (const float*)d_in[3];
  const float* wx1 = (const float*)d_in[4];
  const float* bx1 = (const float*)d_in[5];
  const float* wh1 = (const float*)d_in[6];
  const float* wy  = (const float*)d_in[7];
  const float* by  = (const float*)d_in[8];
  float* out = (float*)d_out;

  // zero flags + pub buffers (h(-1)=h(-2)=0, flags=0) -> every replay identical
  hipMemsetAsync(d_ws, 0, WS_BYTES, stream);
  gru_persist<<<dim3(NBLK), dim3(THREADS), LDS_BYTES, stream>>>(
      x, wx0, bx0, wh0, wx1, bx1, wh1, wy, by, out, (unsigned char*)d_ws);
}